// Round 1
// baseline (1248.858 us; speedup 1.0000x reference)
//
#include <hip/hip_runtime.h>
#include <hip/hip_bf16.h>
#include <math.h>

// Problem constants
#define B_  2
#define N_  6
#define C_  64
#define FH_ 16
#define FW_ 44
#define D_  64
#define PIX (FH_*FW_)          // 704
#define BNI (B_*N_)            // 12
#define BEVH 128
#define BEVW 128
#define BEVC (BEVH*BEVW)       // 16384

// ---------------------------------------------------------------------------
// Kernel T: transpose features [bn][c][p] -> x_t [bn][p][c], and
//           conv2_w [d][c] -> w2t [c][d]
// ---------------------------------------------------------------------------
__global__ void k_transpose(const float* __restrict__ feat,
                            float* __restrict__ x_t,
                            const float* __restrict__ w2,
                            float* __restrict__ w2t) {
    int idx = blockIdx.x * 256 + threadIdx.x;
    if (idx < BNI * C_ * PIX) {
        int bn = idx / (C_ * PIX);
        int r  = idx % (C_ * PIX);
        int c  = r / PIX;
        int p  = r % PIX;
        x_t[(bn * PIX + p) * C_ + c] = feat[idx];
    }
    if (idx < D_ * C_) {
        int d = idx / C_, c = idx % C_;
        w2t[c * D_ + d] = w2[idx];
    }
}

// ---------------------------------------------------------------------------
// Kernel A: conv1 (3x3 SAME) + bias + BN + ReLU.
// One block per (bn, o). Input plane staged in padded LDS (zero halo).
// Output written pillar-major: h_t[(bn*704+p)*64 + o].
// ---------------------------------------------------------------------------
__global__ __launch_bounds__(256) void k_conv1(const float* __restrict__ feat,
                                               const float* __restrict__ w1,
                                               const float* __restrict__ b1,
                                               const float* __restrict__ gma,
                                               const float* __restrict__ bta,
                                               const float* __restrict__ mu,
                                               const float* __restrict__ var,
                                               float* __restrict__ h_t) {
    const int blk = blockIdx.x;
    const int bn  = blk >> 6;
    const int o   = blk & 63;
    const int tid = threadIdx.x;

    __shared__ float wts[C_ * 9];            // 2304 B
    __shared__ float xp[(FH_ + 2) * (FW_ + 2)]; // 18*46 padded plane

    for (int t = tid; t < C_ * 9; t += 256) wts[t] = w1[o * C_ * 9 + t];
    for (int t = tid; t < (FH_ + 2) * (FW_ + 2); t += 256) xp[t] = 0.0f;

    float acc0 = 0.f, acc1 = 0.f, acc2 = 0.f;
    const int p0 = tid, p1 = tid + 256, p2 = tid + 512;
    const int y0 = p0 / FW_, x0 = p0 % FW_;
    const int y1 = p1 / FW_, x1 = p1 % FW_;
    const int y2 = p2 / FW_, x2 = p2 % FW_;

    for (int i = 0; i < C_; ++i) {
        __syncthreads();
        for (int t = tid; t < PIX; t += 256) {
            int y = t / FW_, x = t % FW_;
            xp[(y + 1) * (FW_ + 2) + (x + 1)] = feat[(bn * C_ + i) * PIX + t];
        }
        __syncthreads();
        const float* wr = &wts[i * 9];
        {
            const float* bb = &xp[y0 * (FW_ + 2) + x0];
            acc0 += bb[0]*wr[0] + bb[1]*wr[1] + bb[2]*wr[2]
                  + bb[46]*wr[3] + bb[47]*wr[4] + bb[48]*wr[5]
                  + bb[92]*wr[6] + bb[93]*wr[7] + bb[94]*wr[8];
        }
        {
            const float* bb = &xp[y1 * (FW_ + 2) + x1];
            acc1 += bb[0]*wr[0] + bb[1]*wr[1] + bb[2]*wr[2]
                  + bb[46]*wr[3] + bb[47]*wr[4] + bb[48]*wr[5]
                  + bb[92]*wr[6] + bb[93]*wr[7] + bb[94]*wr[8];
        }
        if (tid < PIX - 512) {
            const float* bb = &xp[y2 * (FW_ + 2) + x2];
            acc2 += bb[0]*wr[0] + bb[1]*wr[1] + bb[2]*wr[2]
                  + bb[46]*wr[3] + bb[47]*wr[4] + bb[48]*wr[5]
                  + bb[92]*wr[6] + bb[93]*wr[7] + bb[94]*wr[8];
        }
    }

    const float bias  = b1[o];
    const float scale = gma[o] / sqrtf(var[o] + 1e-5f);
    const float beta  = bta[o];
    const float mean  = mu[o];

    float v0 = (acc0 + bias - mean) * scale + beta; v0 = v0 > 0.f ? v0 : 0.f;
    float v1 = (acc1 + bias - mean) * scale + beta; v1 = v1 > 0.f ? v1 : 0.f;
    h_t[(bn * PIX + p0) * C_ + o] = v0;
    h_t[(bn * PIX + p1) * C_ + o] = v1;
    if (tid < PIX - 512) {
        float v2 = (acc2 + bias - mean) * scale + beta; v2 = v2 > 0.f ? v2 : 0.f;
        h_t[(bn * PIX + p2) * C_ + o] = v2;
    }
}

// ---------------------------------------------------------------------------
// Kernel B: per pillar (one wave of 64): 1x1 conv -> softmax over D ->
// geometry (double) -> scatter-add 64 channels into BEV.
// ---------------------------------------------------------------------------
__global__ __launch_bounds__(64) void k_scatter(const float* __restrict__ h_t,
                                                const float* __restrict__ x_t,
                                                const float* __restrict__ w2t,
                                                const float* __restrict__ b2,
                                                const float* __restrict__ intr,
                                                const float* __restrict__ extr,
                                                float* __restrict__ out) {
    const int pillar = blockIdx.x;           // 0..8447
    const int bn = pillar / PIX;
    const int p  = pillar % PIX;
    const int b  = bn / N_;
    const int n  = bn % N_;
    const int yi = p / FW_;
    const int xi = p % FW_;
    const int d  = threadIdx.x;              // depth bin = lane

    __shared__ float hs[C_];
    __shared__ float xs[C_];
    hs[d] = h_t[pillar * C_ + d];
    xs[d] = x_t[pillar * C_ + d];
    __syncthreads();

    // 1x1 conv: logit[d] = sum_c h[c] * w2[d][c] + b2[d]
    float logit = b2[d];
#pragma unroll
    for (int c = 0; c < C_; ++c) logit += hs[c] * w2t[c * D_ + d];

    // wave-wide softmax over 64 lanes
    float m = logit;
#pragma unroll
    for (int off = 32; off; off >>= 1) m = fmaxf(m, __shfl_xor(m, off));
    float e = expf(logit - m);
    float s = e;
#pragma unroll
    for (int off = 32; off; off >>= 1) s += __shfl_xor(s, off);
    const float depth = e / s;

    // geometry in double precision
    const double dd = 1.0 + (double)d * (59.0 / 63.0);
    const double px = ((double)xi * (703.0 / 43.0)) * dd;
    const double py = ((double)yi * 17.0) * dd;

    const float* K = &intr[(b * N_ + n) * 9];
    const double a00 = K[0], a01 = K[1], a02 = K[2];
    const double a10 = K[3], a11 = K[4], a12 = K[5];
    const double a20 = K[6], a21 = K[7], a22 = K[8];
    const double det = a00 * (a11 * a22 - a12 * a21)
                     - a01 * (a10 * a22 - a12 * a20)
                     + a02 * (a10 * a21 - a11 * a20);
    const double id = 1.0 / det;
    const double i00 = (a11 * a22 - a12 * a21) * id;
    const double i01 = (a02 * a21 - a01 * a22) * id;
    const double i02 = (a01 * a12 - a02 * a11) * id;
    const double i10 = (a12 * a20 - a10 * a22) * id;
    const double i11 = (a00 * a22 - a02 * a20) * id;
    const double i12 = (a02 * a10 - a00 * a12) * id;
    const double i20 = (a10 * a21 - a11 * a20) * id;
    const double i21 = (a01 * a20 - a00 * a21) * id;
    const double i22 = (a00 * a11 - a01 * a10) * id;

    const double cx = i00 * px + i01 * py + i02 * dd;
    const double cy = i10 * px + i11 * py + i12 * dd;
    const double cz = i20 * px + i21 * py + i22 * dd;

    const float* E = &extr[(b * N_ + n) * 16];
    const double ex = (double)E[0] * cx + (double)E[1] * cy + (double)E[2] * cz + (double)E[3];
    const double ey = (double)E[4] * cx + (double)E[5] * cy + (double)E[6] * cz + (double)E[7];

    const double sx = (ex + 51.2) / 102.4 * 128.0;
    const double sy = (ey + 51.2) / 102.4 * 128.0;
    const int ix = (int)floor(sx);
    const int iy = (int)floor(sy);
    const bool valid = (ix >= 0) && (ix < BEVW) && (iy >= 0) && (iy < BEVH);

    if (valid) {
        const int cell = iy * BEVW + ix;
        float* ob = out + (size_t)b * C_ * BEVC + cell;
#pragma unroll
        for (int c = 0; c < C_; ++c) {
            atomicAdd(ob + c * BEVC, xs[c] * depth);
        }
    }
}

// ---------------------------------------------------------------------------
extern "C" void kernel_launch(void* const* d_in, const int* in_sizes, int n_in,
                              void* d_out, int out_size, void* d_ws, size_t ws_size,
                              hipStream_t stream) {
    const float* feat  = (const float*)d_in[0];
    const float* intr  = (const float*)d_in[1];
    const float* extr  = (const float*)d_in[2];
    const float* w1    = (const float*)d_in[3];
    const float* b1    = (const float*)d_in[4];
    const float* gma   = (const float*)d_in[5];
    const float* bta   = (const float*)d_in[6];
    const float* mu    = (const float*)d_in[7];
    const float* var   = (const float*)d_in[8];
    const float* w2    = (const float*)d_in[9];
    const float* b2    = (const float*)d_in[10];
    float* out = (float*)d_out;

    // workspace layout
    float* h_t = (float*)d_ws;                       // 540672 f32
    float* x_t = h_t + (size_t)BNI * PIX * C_;       // 540672 f32
    float* w2t = x_t + (size_t)BNI * PIX * C_;       // 4096 f32

    // zero output (atomics accumulate into it)
    hipMemsetAsync(d_out, 0, (size_t)out_size * sizeof(float), stream);

    // transpose features + conv2 weights
    {
        int total = BNI * C_ * PIX;
        int blocks = (total + 255) / 256;
        k_transpose<<<blocks, 256, 0, stream>>>(feat, x_t, w2, w2t);
    }
    // conv1 + BN + ReLU
    k_conv1<<<BNI * C_, 256, 0, stream>>>(feat, w1, b1, gma, bta, mu, var, h_t);
    // 1x1 conv + softmax + geometry + scatter
    k_scatter<<<BNI * PIX, 64, 0, stream>>>(h_t, x_t, w2t, b2, intr, extr, out);

    (void)in_sizes; (void)n_in; (void)ws_size;
}

// Round 2
// 244.701 us; speedup vs baseline: 5.1036x; 5.1036x over previous
//
#include <hip/hip_runtime.h>
#include <hip/hip_bf16.h>
#include <math.h>

// Problem constants
#define B_  2
#define N_  6
#define C_  64
#define FH_ 16
#define FW_ 44
#define D_  64
#define PIX (FH_*FW_)          // 704
#define BNI (B_*N_)            // 12
#define NPILLAR (BNI*PIX)      // 8448
#define NPOINT (NPILLAR*D_)    // 540672
#define BEVH 128
#define BEVW 128
#define BEVC (BEVH*BEVW)       // 16384
#define NCELL (B_*BEVC)        // 32768

typedef unsigned int u32;

// ---------------------------------------------------------------------------
// Kernel T: transpose features [bn][c][p] -> x_t [bn][p][c], transpose w2,
// and zero the cell counters.
// ---------------------------------------------------------------------------
__global__ void k_transpose(const float* __restrict__ feat,
                            float* __restrict__ x_t,
                            const float* __restrict__ w2,
                            float* __restrict__ w2t,
                            u32* __restrict__ counts) {
    int idx = blockIdx.x * 256 + threadIdx.x;
    if (idx < NPOINT) {   // NPOINT == BNI*C_*PIX here (64*704 per bn both ways)
        int bn = idx / (C_ * PIX);
        int r  = idx % (C_ * PIX);
        int c  = r / PIX;
        int p  = r % PIX;
        x_t[(bn * PIX + p) * C_ + c] = feat[idx];
    }
    if (idx < D_ * C_) {
        int d = idx / C_, c = idx % C_;
        w2t[c * D_ + d] = w2[idx];
    }
    if (idx < NCELL) counts[idx] = 0;
}

// ---------------------------------------------------------------------------
// Kernel A: conv1 (3x3 SAME) + bias + BN + ReLU. One block per (bn, o).
// ---------------------------------------------------------------------------
__global__ __launch_bounds__(256) void k_conv1(const float* __restrict__ feat,
                                               const float* __restrict__ w1,
                                               const float* __restrict__ b1,
                                               const float* __restrict__ gma,
                                               const float* __restrict__ bta,
                                               const float* __restrict__ mu,
                                               const float* __restrict__ var,
                                               float* __restrict__ h_t) {
    const int blk = blockIdx.x;
    const int bn  = blk >> 6;
    const int o   = blk & 63;
    const int tid = threadIdx.x;

    __shared__ float wts[C_ * 9];
    __shared__ float xp[(FH_ + 2) * (FW_ + 2)];

    for (int t = tid; t < C_ * 9; t += 256) wts[t] = w1[o * C_ * 9 + t];
    for (int t = tid; t < (FH_ + 2) * (FW_ + 2); t += 256) xp[t] = 0.0f;

    float acc0 = 0.f, acc1 = 0.f, acc2 = 0.f;
    const int p0 = tid, p1 = tid + 256, p2 = tid + 512;
    const int y0 = p0 / FW_, x0 = p0 % FW_;
    const int y1 = p1 / FW_, x1 = p1 % FW_;
    const int y2 = p2 / FW_, x2 = p2 % FW_;

    for (int i = 0; i < C_; ++i) {
        __syncthreads();
        for (int t = tid; t < PIX; t += 256) {
            int y = t / FW_, x = t % FW_;
            xp[(y + 1) * (FW_ + 2) + (x + 1)] = feat[(bn * C_ + i) * PIX + t];
        }
        __syncthreads();
        const float* wr = &wts[i * 9];
        {
            const float* bb = &xp[y0 * (FW_ + 2) + x0];
            acc0 += bb[0]*wr[0] + bb[1]*wr[1] + bb[2]*wr[2]
                  + bb[46]*wr[3] + bb[47]*wr[4] + bb[48]*wr[5]
                  + bb[92]*wr[6] + bb[93]*wr[7] + bb[94]*wr[8];
        }
        {
            const float* bb = &xp[y1 * (FW_ + 2) + x1];
            acc1 += bb[0]*wr[0] + bb[1]*wr[1] + bb[2]*wr[2]
                  + bb[46]*wr[3] + bb[47]*wr[4] + bb[48]*wr[5]
                  + bb[92]*wr[6] + bb[93]*wr[7] + bb[94]*wr[8];
        }
        if (tid < PIX - 512) {
            const float* bb = &xp[y2 * (FW_ + 2) + x2];
            acc2 += bb[0]*wr[0] + bb[1]*wr[1] + bb[2]*wr[2]
                  + bb[46]*wr[3] + bb[47]*wr[4] + bb[48]*wr[5]
                  + bb[92]*wr[6] + bb[93]*wr[7] + bb[94]*wr[8];
        }
    }

    const float bias  = b1[o];
    const float scale = gma[o] / sqrtf(var[o] + 1e-5f);
    const float beta  = bta[o];
    const float mean  = mu[o];

    float v0 = (acc0 + bias - mean) * scale + beta; v0 = v0 > 0.f ? v0 : 0.f;
    float v1 = (acc1 + bias - mean) * scale + beta; v1 = v1 > 0.f ? v1 : 0.f;
    h_t[(bn * PIX + p0) * C_ + o] = v0;
    h_t[(bn * PIX + p1) * C_ + o] = v1;
    if (tid < PIX - 512) {
        float v2 = (acc2 + bias - mean) * scale + beta; v2 = v2 > 0.f ? v2 : 0.f;
        h_t[(bn * PIX + p2) * C_ + o] = v2;
    }
}

// ---------------------------------------------------------------------------
// Kernel D: per pillar wave: 1x1 conv -> softmax -> geometry (double) ->
// store weight + cell id per point, bump per-cell counter.
// ---------------------------------------------------------------------------
__global__ __launch_bounds__(64) void k_depth(const float* __restrict__ h_t,
                                              const float* __restrict__ w2t,
                                              const float* __restrict__ b2,
                                              const float* __restrict__ intr,
                                              const float* __restrict__ extr,
                                              float* __restrict__ wgt,
                                              int* __restrict__ cellid,
                                              u32* __restrict__ counts) {
    const int pillar = blockIdx.x;           // 0..8447
    const int bn = pillar / PIX;
    const int p  = pillar % PIX;
    const int b  = bn / N_;
    const int n  = bn % N_;
    const int yi = p / FW_;
    const int xi = p % FW_;
    const int d  = threadIdx.x;              // depth bin = lane

    __shared__ float hs[C_];
    hs[d] = h_t[pillar * C_ + d];
    __syncthreads();

    float logit = b2[d];
#pragma unroll
    for (int c = 0; c < C_; ++c) logit += hs[c] * w2t[c * D_ + d];

    float m = logit;
#pragma unroll
    for (int off = 32; off; off >>= 1) m = fmaxf(m, __shfl_xor(m, off));
    float e = expf(logit - m);
    float s = e;
#pragma unroll
    for (int off = 32; off; off >>= 1) s += __shfl_xor(s, off);
    const float depth = e / s;

    // geometry in double precision
    const double dd = 1.0 + (double)d * (59.0 / 63.0);
    const double px = ((double)xi * (703.0 / 43.0)) * dd;
    const double py = ((double)yi * 17.0) * dd;

    const float* K = &intr[(b * N_ + n) * 9];
    const double a00 = K[0], a01 = K[1], a02 = K[2];
    const double a10 = K[3], a11 = K[4], a12 = K[5];
    const double a20 = K[6], a21 = K[7], a22 = K[8];
    const double det = a00 * (a11 * a22 - a12 * a21)
                     - a01 * (a10 * a22 - a12 * a20)
                     + a02 * (a10 * a21 - a11 * a20);
    const double id = 1.0 / det;
    const double i00 = (a11 * a22 - a12 * a21) * id;
    const double i01 = (a02 * a21 - a01 * a22) * id;
    const double i02 = (a01 * a12 - a02 * a11) * id;
    const double i10 = (a12 * a20 - a10 * a22) * id;
    const double i11 = (a00 * a22 - a02 * a20) * id;
    const double i12 = (a02 * a10 - a00 * a12) * id;
    const double i20 = (a10 * a21 - a11 * a20) * id;
    const double i21 = (a01 * a20 - a00 * a21) * id;
    const double i22 = (a00 * a11 - a01 * a10) * id;

    const double cx = i00 * px + i01 * py + i02 * dd;
    const double cy = i10 * px + i11 * py + i12 * dd;
    const double cz = i20 * px + i21 * py + i22 * dd;

    const float* E = &extr[(b * N_ + n) * 16];
    const double ex = (double)E[0] * cx + (double)E[1] * cy + (double)E[2] * cz + (double)E[3];
    const double ey = (double)E[4] * cx + (double)E[5] * cy + (double)E[6] * cz + (double)E[7];

    const double sx = (ex + 51.2) / 102.4 * 128.0;
    const double sy = (ey + 51.2) / 102.4 * 128.0;
    const int ix = (int)floor(sx);
    const int iy = (int)floor(sy);
    const bool valid = (ix >= 0) && (ix < BEVW) && (iy >= 0) && (iy < BEVH);

    const int i = pillar * D_ + d;
    wgt[i] = depth;
    if (valid) {
        const int cell = b * BEVC + iy * BEVW + ix;
        cellid[i] = cell;
        atomicAdd(&counts[cell], 1u);
    } else {
        cellid[i] = -1;
    }
}

// ---------------------------------------------------------------------------
// Kernel S: single-block exclusive scan over NCELL counters -> offsets.
// Also resets counts to 0 (reused as placement cursors).
// ---------------------------------------------------------------------------
__global__ __launch_bounds__(1024) void k_scan(u32* __restrict__ counts,
                                               u32* __restrict__ offsets) {
    const int tid  = threadIdx.x;
    const int lane = tid & 63;
    const int wid  = tid >> 6;              // 16 waves
    __shared__ u32 wexcl[16];
    __shared__ u32 chunk_tot;
    __shared__ u32 carry_s;
    if (tid == 0) carry_s = 0;
    __syncthreads();

    for (int ch = 0; ch < NCELL / 1024; ++ch) {
        const int i = ch * 1024 + tid;
        u32 v = counts[i];
        // wave-inclusive scan
        u32 incl = v;
#pragma unroll
        for (int off = 1; off < 64; off <<= 1) {
            u32 t = __shfl_up(incl, off);
            if (lane >= off) incl += t;
        }
        if (lane == 63) wexcl[wid] = incl;
        __syncthreads();
        if (wid == 0) {
            u32 wsv = (lane < 16) ? wexcl[lane] : 0;
            u32 wsi = wsv;
#pragma unroll
            for (int off = 1; off < 16; off <<= 1) {
                u32 t = __shfl_up(wsi, off);
                if (lane >= off) wsi += t;
            }
            if (lane < 16) wexcl[lane] = wsi - wsv;   // exclusive wave base
            if (lane == 15) chunk_tot = wsi;
        }
        __syncthreads();
        const u32 carry = carry_s;
        offsets[i] = carry + wexcl[wid] + incl - v;
        counts[i] = 0;
        __syncthreads();
        if (tid == 0) carry_s = carry + chunk_tot;
        __syncthreads();
    }
    if (tid == 0) offsets[NCELL] = carry_s;
}

// ---------------------------------------------------------------------------
// Kernel P: counting-sort placement: sorted[] gets point indices grouped by
// cell. counts[] (zeroed by k_scan) serves as per-cell cursor.
// ---------------------------------------------------------------------------
__global__ void k_place(const int* __restrict__ cellid,
                        const u32* __restrict__ offsets,
                        u32* __restrict__ counts,
                        u32* __restrict__ sorted) {
    const int i = blockIdx.x * 256 + threadIdx.x;
    if (i >= NPOINT) return;
    const int c = cellid[i];
    if (c >= 0) {
        const u32 pos = offsets[c] + atomicAdd(&counts[c], 1u);
        sorted[pos] = (u32)i;
    }
}

// ---------------------------------------------------------------------------
// Kernel G: gather-pool. One block (4 waves) per (b,cell); lane = channel.
// No atomics; writes every output cell exactly once.
// ---------------------------------------------------------------------------
__global__ __launch_bounds__(256) void k_pool(const u32* __restrict__ sorted,
                                              const u32* __restrict__ offsets,
                                              const float* __restrict__ wgt,
                                              const float* __restrict__ x_t,
                                              float* __restrict__ out) {
    const int bcell = blockIdx.x;            // 0..NCELL-1
    const int b     = bcell >> 14;           // /BEVC
    const int cell  = bcell & (BEVC - 1);
    const int tid   = threadIdx.x;
    const int lane  = tid & 63;              // channel
    const int wv    = tid >> 6;              // 0..3

    const u32 start = offsets[bcell];
    const u32 end   = offsets[bcell + 1];

    float acc = 0.f;
    for (u32 j = start + wv; j < end; j += 4) {
        const u32 idx = sorted[j];
        const float wp = wgt[idx];
        const u32 pillar = idx >> 6;
        acc += wp * x_t[pillar * C_ + lane];
    }

    __shared__ float sacc[256];
    sacc[tid] = acc;
    __syncthreads();
    if (tid < 64) {
        float v = sacc[tid] + sacc[tid + 64] + sacc[tid + 128] + sacc[tid + 192];
        out[((size_t)b * C_ + lane) * BEVC + cell] = v;
    }
}

// ---------------------------------------------------------------------------
extern "C" void kernel_launch(void* const* d_in, const int* in_sizes, int n_in,
                              void* d_out, int out_size, void* d_ws, size_t ws_size,
                              hipStream_t stream) {
    const float* feat  = (const float*)d_in[0];
    const float* intr  = (const float*)d_in[1];
    const float* extr  = (const float*)d_in[2];
    const float* w1    = (const float*)d_in[3];
    const float* b1    = (const float*)d_in[4];
    const float* gma   = (const float*)d_in[5];
    const float* bta   = (const float*)d_in[6];
    const float* mu    = (const float*)d_in[7];
    const float* var   = (const float*)d_in[8];
    const float* w2    = (const float*)d_in[9];
    const float* b2    = (const float*)d_in[10];
    float* out = (float*)d_out;

    // workspace layout (floats/u32s, all 4B)
    float* h_t    = (float*)d_ws;                       // NPOINT
    float* x_t    = h_t + NPOINT;                       // NPOINT
    float* w2t    = x_t + NPOINT;                       // 4096
    float* wgt    = w2t + 4096;                         // NPOINT
    int*   cellid = (int*)(wgt + NPOINT);               // NPOINT
    u32*   counts = (u32*)(cellid + NPOINT);            // NCELL
    u32*   offs   = counts + NCELL;                     // NCELL+1
    u32*   sorted = offs + NCELL + 1;                   // NPOINT

    {
        int blocks = (NPOINT + 255) / 256;
        k_transpose<<<blocks, 256, 0, stream>>>(feat, x_t, w2, w2t, counts);
    }
    k_conv1<<<BNI * C_, 256, 0, stream>>>(feat, w1, b1, gma, bta, mu, var, h_t);
    k_depth<<<NPILLAR, 64, 0, stream>>>(h_t, w2t, b2, intr, extr, wgt, cellid, counts);
    k_scan<<<1, 1024, 0, stream>>>(counts, offs);
    k_place<<<(NPOINT + 255) / 256, 256, 0, stream>>>(cellid, offs, counts, sorted);
    k_pool<<<NCELL, 256, 0, stream>>>(sorted, offs, wgt, x_t, out);

    (void)in_sizes; (void)n_in; (void)ws_size; (void)out_size;
}

// Round 3
// 186.358 us; speedup vs baseline: 6.7014x; 1.3131x over previous
//
#include <hip/hip_runtime.h>
#include <hip/hip_bf16.h>
#include <math.h>

// Problem constants
#define B_  2
#define N_  6
#define C_  64
#define FH_ 16
#define FW_ 44
#define D_  64
#define PIX (FH_*FW_)          // 704
#define BNI (B_*N_)            // 12
#define NPILLAR (BNI*PIX)      // 8448
#define NPOINT (NPILLAR*D_)    // 540672
#define BEVH 128
#define BEVW 128
#define BEVC (BEVH*BEVW)       // 16384
#define NCELL (B_*BEVC)        // 32768
#define PW 46                  // padded plane width
#define PP (18*PW)             // padded plane size = 828

typedef unsigned int u32;

// ---------------------------------------------------------------------------
// Kernel T: transpose features [bn][c][p] -> x_t [bn][p][c], transpose w2,
// zero cell counters.
// ---------------------------------------------------------------------------
__global__ void k_transpose(const float* __restrict__ feat,
                            float* __restrict__ x_t,
                            const float* __restrict__ w2,
                            float* __restrict__ w2t,
                            u32* __restrict__ counts) {
    int idx = blockIdx.x * 256 + threadIdx.x;
    if (idx < NPOINT) {
        int bn = idx / (C_ * PIX);
        int r  = idx % (C_ * PIX);
        int c  = r / PIX;
        int p  = r % PIX;
        x_t[(bn * PIX + p) * C_ + c] = feat[idx];
    }
    if (idx < D_ * C_) {
        int d = idx / C_, c = idx % C_;
        w2t[c * D_ + d] = w2[idx];
    }
    if (idx < NCELL) counts[idx] = 0;
}

// ---------------------------------------------------------------------------
// Kernel A: conv1 (3x3 SAME) + bias + BN + ReLU.
// Grid: 192 blocks = bn(12) x ogroup(16, 4 outputs each). Block: 704 threads,
// one per pixel. Double-buffered LDS plane, register prefetch, 1 barrier/iter.
// Weights via block-uniform global reads (SGPR path). Output: float4/pillar.
// ---------------------------------------------------------------------------
__global__ __launch_bounds__(704) void k_conv1(const float* __restrict__ feat,
                                               const float* __restrict__ w1,
                                               const float* __restrict__ b1,
                                               const float* __restrict__ gma,
                                               const float* __restrict__ bta,
                                               const float* __restrict__ mu,
                                               const float* __restrict__ var,
                                               float* __restrict__ h_t) {
    const int blk = blockIdx.x;
    const int bn  = blk >> 4;
    const int o0  = (blk & 15) * 4;
    const int tid = threadIdx.x;           // pixel 0..703
    const int y   = tid / FW_;
    const int x   = tid % FW_;
    const int wpos = (y + 1) * PW + (x + 1);
    const int rpos = y * PW + x;           // top-left of 3x3 window

    __shared__ float xp[2][PP];

    // zero both buffers once (halo must be 0; interior overwritten each iter)
    for (int t = tid; t < 2 * PP; t += 704) ((float*)xp)[t] = 0.0f;

    const float* fbase = feat + (size_t)bn * C_ * PIX + tid;
    float vload = fbase[0];
    __syncthreads();                        // zeroing complete
    xp[0][wpos] = vload;
    vload = fbase[PIX];
    __syncthreads();                        // plane 0 visible

    float acc0 = 0.f, acc1 = 0.f, acc2 = 0.f, acc3 = 0.f;

#pragma unroll 2
    for (int i = 0; i < C_; ++i) {
        const int cb = i & 1;
        if (i < C_ - 1) xp[cb ^ 1][wpos] = vload;       // stage next plane
        if (i < C_ - 2) vload = fbase[(i + 2) * PIX];   // prefetch plane i+2

        const float* bb = &xp[cb][rpos];
        const float n0 = bb[0],      n1 = bb[1],      n2 = bb[2];
        const float n3 = bb[PW],     n4 = bb[PW+1],   n5 = bb[PW+2];
        const float n6 = bb[2*PW],   n7 = bb[2*PW+1], n8 = bb[2*PW+2];

        const float* wr0 = w1 + ((size_t)(o0 + 0) * C_ + i) * 9;
        const float* wr1 = w1 + ((size_t)(o0 + 1) * C_ + i) * 9;
        const float* wr2 = w1 + ((size_t)(o0 + 2) * C_ + i) * 9;
        const float* wr3 = w1 + ((size_t)(o0 + 3) * C_ + i) * 9;
        acc0 += n0*wr0[0] + n1*wr0[1] + n2*wr0[2] + n3*wr0[3] + n4*wr0[4]
              + n5*wr0[5] + n6*wr0[6] + n7*wr0[7] + n8*wr0[8];
        acc1 += n0*wr1[0] + n1*wr1[1] + n2*wr1[2] + n3*wr1[3] + n4*wr1[4]
              + n5*wr1[5] + n6*wr1[6] + n7*wr1[7] + n8*wr1[8];
        acc2 += n0*wr2[0] + n1*wr2[1] + n2*wr2[2] + n3*wr2[3] + n4*wr2[4]
              + n5*wr2[5] + n6*wr2[6] + n7*wr2[7] + n8*wr2[8];
        acc3 += n0*wr3[0] + n1*wr3[1] + n2*wr3[2] + n3*wr3[3] + n4*wr3[4]
              + n5*wr3[5] + n6*wr3[6] + n7*wr3[7] + n8*wr3[8];
        __syncthreads();
    }

    float4 r;
    {
        const float sc = gma[o0+0] / sqrtf(var[o0+0] + 1e-5f);
        float v = (acc0 + b1[o0+0] - mu[o0+0]) * sc + bta[o0+0];
        r.x = v > 0.f ? v : 0.f;
    }
    {
        const float sc = gma[o0+1] / sqrtf(var[o0+1] + 1e-5f);
        float v = (acc1 + b1[o0+1] - mu[o0+1]) * sc + bta[o0+1];
        r.y = v > 0.f ? v : 0.f;
    }
    {
        const float sc = gma[o0+2] / sqrtf(var[o0+2] + 1e-5f);
        float v = (acc2 + b1[o0+2] - mu[o0+2]) * sc + bta[o0+2];
        r.z = v > 0.f ? v : 0.f;
    }
    {
        const float sc = gma[o0+3] / sqrtf(var[o0+3] + 1e-5f);
        float v = (acc3 + b1[o0+3] - mu[o0+3]) * sc + bta[o0+3];
        r.w = v > 0.f ? v : 0.f;
    }
    *(float4*)&h_t[((size_t)(bn * PIX + tid)) * C_ + o0] = r;
}

// ---------------------------------------------------------------------------
// Kernel D: 4 pillars per block (one wave each): 1x1 conv -> softmax ->
// geometry (double) -> weight + cell id per point, bump per-cell counter.
// ---------------------------------------------------------------------------
__global__ __launch_bounds__(256) void k_depth(const float* __restrict__ h_t,
                                               const float* __restrict__ w2t,
                                               const float* __restrict__ b2,
                                               const float* __restrict__ intr,
                                               const float* __restrict__ extr,
                                               float* __restrict__ wgt,
                                               int* __restrict__ cellid,
                                               u32* __restrict__ counts) {
    const int wv = threadIdx.x >> 6;
    const int d  = threadIdx.x & 63;
    const int pillar = blockIdx.x * 4 + wv;   // 8448 = 2112*4
    const int bn = pillar / PIX;
    const int p  = pillar % PIX;
    const int b  = bn / N_;
    const int n  = bn % N_;
    const int yi = p / FW_;
    const int xi = p % FW_;

    __shared__ float hs[4][C_];
    hs[wv][d] = h_t[(size_t)pillar * C_ + d];
    __syncthreads();

    float logit = b2[d];
#pragma unroll
    for (int c = 0; c < C_; ++c) logit += hs[wv][c] * w2t[c * D_ + d];

    float m = logit;
#pragma unroll
    for (int off = 32; off; off >>= 1) m = fmaxf(m, __shfl_xor(m, off));
    float e = expf(logit - m);
    float s = e;
#pragma unroll
    for (int off = 32; off; off >>= 1) s += __shfl_xor(s, off);
    const float depth = e / s;

    // geometry in double precision
    const double dd = 1.0 + (double)d * (59.0 / 63.0);
    const double px = ((double)xi * (703.0 / 43.0)) * dd;
    const double py = ((double)yi * 17.0) * dd;

    const float* K = &intr[(b * N_ + n) * 9];
    const double a00 = K[0], a01 = K[1], a02 = K[2];
    const double a10 = K[3], a11 = K[4], a12 = K[5];
    const double a20 = K[6], a21 = K[7], a22 = K[8];
    const double det = a00 * (a11 * a22 - a12 * a21)
                     - a01 * (a10 * a22 - a12 * a20)
                     + a02 * (a10 * a21 - a11 * a20);
    const double id = 1.0 / det;
    const double i00 = (a11 * a22 - a12 * a21) * id;
    const double i01 = (a02 * a21 - a01 * a22) * id;
    const double i02 = (a01 * a12 - a02 * a11) * id;
    const double i10 = (a12 * a20 - a10 * a22) * id;
    const double i11 = (a00 * a22 - a02 * a20) * id;
    const double i12 = (a02 * a10 - a00 * a12) * id;
    const double i20 = (a10 * a21 - a11 * a20) * id;
    const double i21 = (a01 * a20 - a00 * a21) * id;
    const double i22 = (a00 * a11 - a01 * a10) * id;

    const double cx = i00 * px + i01 * py + i02 * dd;
    const double cy = i10 * px + i11 * py + i12 * dd;
    const double cz = i20 * px + i21 * py + i22 * dd;

    const float* E = &extr[(b * N_ + n) * 16];
    const double ex = (double)E[0] * cx + (double)E[1] * cy + (double)E[2] * cz + (double)E[3];
    const double ey = (double)E[4] * cx + (double)E[5] * cy + (double)E[6] * cz + (double)E[7];

    const double sx = (ex + 51.2) / 102.4 * 128.0;
    const double sy = (ey + 51.2) / 102.4 * 128.0;
    const int ix = (int)floor(sx);
    const int iy = (int)floor(sy);
    const bool valid = (ix >= 0) && (ix < BEVW) && (iy >= 0) && (iy < BEVH);

    const int i = pillar * D_ + d;
    wgt[i] = depth;
    if (valid) {
        const int cell = b * BEVC + iy * BEVW + ix;
        cellid[i] = cell;
        atomicAdd(&counts[cell], 1u);
    } else {
        cellid[i] = -1;
    }
}

// ---------------------------------------------------------------------------
// Kernel S: single-block scan, 32 cells per thread in registers, 2 barriers.
// Writes exclusive offsets, zeros counts (reused as cursors).
// ---------------------------------------------------------------------------
__global__ __launch_bounds__(1024) void k_scan(u32* __restrict__ counts,
                                               u32* __restrict__ offsets) {
    const int tid  = threadIdx.x;
    const int lane = tid & 63;
    const int wid  = tid >> 6;              // 16 waves
    const int base = tid * 32;

    u32 v[32];
    u32 run = 0;
#pragma unroll
    for (int k = 0; k < 32; ++k) {
        u32 t = counts[base + k];
        v[k] = run;                          // exclusive within thread
        run += t;
    }

    // wave-inclusive scan of per-thread totals
    u32 incl = run;
#pragma unroll
    for (int off = 1; off < 64; off <<= 1) {
        u32 t = __shfl_up(incl, off);
        if (lane >= off) incl += t;
    }
    const u32 wexcl = incl - run;

    __shared__ u32 wtot[16], web[16];
    if (lane == 63) wtot[wid] = incl;
    __syncthreads();
    if (tid == 0) {
        u32 s = 0;
        for (int j = 0; j < 16; ++j) { u32 t = wtot[j]; web[j] = s; s += t; }
    }
    __syncthreads();
    const u32 tbase = web[wid] + wexcl;

#pragma unroll
    for (int k = 0; k < 32; ++k) {
        offsets[base + k] = tbase + v[k];
        counts[base + k] = 0;
    }
    if (tid == 1023) offsets[NCELL] = tbase + run;
}

// ---------------------------------------------------------------------------
// Kernel P: counting-sort placement.
// ---------------------------------------------------------------------------
__global__ void k_place(const int* __restrict__ cellid,
                        const u32* __restrict__ offsets,
                        u32* __restrict__ counts,
                        u32* __restrict__ sorted) {
    const int i = blockIdx.x * 256 + threadIdx.x;
    if (i >= NPOINT) return;
    const int c = cellid[i];
    if (c >= 0) {
        const u32 pos = offsets[c] + atomicAdd(&counts[c], 1u);
        sorted[pos] = (u32)i;
    }
}

// ---------------------------------------------------------------------------
// Kernel G: gather-pool. One block (4 waves) per (b,cell); lane = channel.
// ---------------------------------------------------------------------------
__global__ __launch_bounds__(256) void k_pool(const u32* __restrict__ sorted,
                                              const u32* __restrict__ offsets,
                                              const float* __restrict__ wgt,
                                              const float* __restrict__ x_t,
                                              float* __restrict__ out) {
    const int bcell = blockIdx.x;            // 0..NCELL-1
    const int b     = bcell >> 14;
    const int cell  = bcell & (BEVC - 1);
    const int tid   = threadIdx.x;
    const int lane  = tid & 63;              // channel
    const int wv    = tid >> 6;              // 0..3

    const u32 start = offsets[bcell];
    const u32 end   = offsets[bcell + 1];

    float acc = 0.f;
    for (u32 j = start + wv; j < end; j += 4) {
        const u32 idx = sorted[j];
        const float wp = wgt[idx];
        const u32 pillar = idx >> 6;
        acc += wp * x_t[(size_t)pillar * C_ + lane];
    }

    __shared__ float sacc[256];
    sacc[tid] = acc;
    __syncthreads();
    if (tid < 64) {
        float v = sacc[tid] + sacc[tid + 64] + sacc[tid + 128] + sacc[tid + 192];
        out[((size_t)b * C_ + lane) * BEVC + cell] = v;
    }
}

// ---------------------------------------------------------------------------
extern "C" void kernel_launch(void* const* d_in, const int* in_sizes, int n_in,
                              void* d_out, int out_size, void* d_ws, size_t ws_size,
                              hipStream_t stream) {
    const float* feat  = (const float*)d_in[0];
    const float* intr  = (const float*)d_in[1];
    const float* extr  = (const float*)d_in[2];
    const float* w1    = (const float*)d_in[3];
    const float* b1    = (const float*)d_in[4];
    const float* gma   = (const float*)d_in[5];
    const float* bta   = (const float*)d_in[6];
    const float* mu    = (const float*)d_in[7];
    const float* var   = (const float*)d_in[8];
    const float* w2    = (const float*)d_in[9];
    const float* b2    = (const float*)d_in[10];
    float* out = (float*)d_out;

    // workspace layout (all 4B elements)
    float* h_t    = (float*)d_ws;                       // NPOINT
    float* x_t    = h_t + NPOINT;                       // NPOINT
    float* w2t    = x_t + NPOINT;                       // 4096
    float* wgt    = w2t + 4096;                         // NPOINT
    int*   cellid = (int*)(wgt + NPOINT);               // NPOINT
    u32*   counts = (u32*)(cellid + NPOINT);            // NCELL
    u32*   offs   = counts + NCELL;                     // NCELL+1
    u32*   sorted = offs + NCELL + 1;                   // NPOINT

    k_transpose<<<(NPOINT + 255) / 256, 256, 0, stream>>>(feat, x_t, w2, w2t, counts);
    k_conv1<<<BNI * 16, 704, 0, stream>>>(feat, w1, b1, gma, bta, mu, var, h_t);
    k_depth<<<NPILLAR / 4, 256, 0, stream>>>(h_t, w2t, b2, intr, extr, wgt, cellid, counts);
    k_scan<<<1, 1024, 0, stream>>>(counts, offs);
    k_place<<<(NPOINT + 255) / 256, 256, 0, stream>>>(cellid, offs, counts, sorted);
    k_pool<<<NCELL, 256, 0, stream>>>(sorted, offs, wgt, x_t, out);

    (void)in_sizes; (void)n_in; (void)ws_size; (void)out_size;
}

// Round 4
// 162.163 us; speedup vs baseline: 7.7012x; 1.1492x over previous
//
#include <hip/hip_runtime.h>
#include <hip/hip_bf16.h>
#include <math.h>

// Problem constants
#define B_  2
#define N_  6
#define C_  64
#define FH_ 16
#define FW_ 44
#define D_  64
#define PIX (FH_*FW_)          // 704
#define BNI (B_*N_)            // 12
#define NPILLAR (BNI*PIX)      // 8448
#define NPOINT (NPILLAR*D_)    // 540672
#define BEVH 128
#define BEVW 128
#define BEVC (BEVH*BEVW)       // 16384
#define NCELL (B_*BEVC)        // 32768
#define PW 46                  // padded plane width
#define PP (18*PW)             // padded plane size = 828

typedef unsigned int u32;

// ---------------------------------------------------------------------------
// Kernel T: LDS-tiled transpose feat [bn][c][p] -> x_t [bn][p][c] (both sides
// coalesced), w2 transpose, zero cell counters.
// Grid: 132 blocks = 12 bn x 11 pixel-tiles of 64.
// ---------------------------------------------------------------------------
__global__ __launch_bounds__(256) void k_transpose(const float* __restrict__ feat,
                                                   float* __restrict__ x_t,
                                                   const float* __restrict__ w2,
                                                   float* __restrict__ w2t,
                                                   u32* __restrict__ counts) {
    const int bn = blockIdx.x / 11;
    const int p0 = (blockIdx.x % 11) * 64;
    const int tid = threadIdx.x;
    const int lane = tid & 63;
    const int row4 = tid >> 6;               // 0..3

    __shared__ float tile[64][65];

#pragma unroll
    for (int k = 0; k < 16; ++k) {
        const int c = k * 4 + row4;
        tile[c][lane] = feat[((size_t)bn * C_ + c) * PIX + p0 + lane];
    }
    __syncthreads();
#pragma unroll
    for (int k = 0; k < 16; ++k) {
        const int r = k * 4 + row4;          // pixel within tile
        x_t[((size_t)bn * PIX + p0 + r) * C_ + lane] = tile[lane][r];
    }

    // w2t (block 0) and counts zeroing (first 128 blocks)
    if (blockIdx.x == 0) {
#pragma unroll
        for (int k = 0; k < 16; ++k) {
            const int idx = k * 256 + tid;   // 4096 = D_*C_
            const int d = idx >> 6, c = idx & 63;
            w2t[c * D_ + d] = w2[idx];
        }
    }
    const int gz = blockIdx.x * 256 + tid;
    if (gz < NCELL) counts[gz] = 0;
}

// ---------------------------------------------------------------------------
// Kernel A: conv1 (3x3 SAME) + bias + BN + ReLU.
// 192 blocks = bn(12) x ogroup(16, 4 outputs). 704 threads = 1/pixel.
// Double-buffered LDS plane, register prefetch, 1 barrier/iter, SGPR weights.
// ---------------------------------------------------------------------------
__global__ __launch_bounds__(704) void k_conv1(const float* __restrict__ feat,
                                               const float* __restrict__ w1,
                                               const float* __restrict__ b1,
                                               const float* __restrict__ gma,
                                               const float* __restrict__ bta,
                                               const float* __restrict__ mu,
                                               const float* __restrict__ var,
                                               float* __restrict__ h_t) {
    const int blk = blockIdx.x;
    const int bn  = blk >> 4;
    const int o0  = (blk & 15) * 4;
    const int tid = threadIdx.x;           // pixel 0..703
    const int y   = tid / FW_;
    const int x   = tid % FW_;
    const int wpos = (y + 1) * PW + (x + 1);
    const int rpos = y * PW + x;

    __shared__ float xp[2][PP];

    for (int t = tid; t < 2 * PP; t += 704) ((float*)xp)[t] = 0.0f;

    const float* fbase = feat + (size_t)bn * C_ * PIX + tid;
    float vload = fbase[0];
    __syncthreads();
    xp[0][wpos] = vload;
    vload = fbase[PIX];
    __syncthreads();

    float acc0 = 0.f, acc1 = 0.f, acc2 = 0.f, acc3 = 0.f;

#pragma unroll 2
    for (int i = 0; i < C_; ++i) {
        const int cb = i & 1;
        if (i < C_ - 1) xp[cb ^ 1][wpos] = vload;
        if (i < C_ - 2) vload = fbase[(i + 2) * PIX];

        const float* bb = &xp[cb][rpos];
        const float n0 = bb[0],      n1 = bb[1],      n2 = bb[2];
        const float n3 = bb[PW],     n4 = bb[PW+1],   n5 = bb[PW+2];
        const float n6 = bb[2*PW],   n7 = bb[2*PW+1], n8 = bb[2*PW+2];

        const float* wr0 = w1 + ((size_t)(o0 + 0) * C_ + i) * 9;
        const float* wr1 = w1 + ((size_t)(o0 + 1) * C_ + i) * 9;
        const float* wr2 = w1 + ((size_t)(o0 + 2) * C_ + i) * 9;
        const float* wr3 = w1 + ((size_t)(o0 + 3) * C_ + i) * 9;
        acc0 += n0*wr0[0] + n1*wr0[1] + n2*wr0[2] + n3*wr0[3] + n4*wr0[4]
              + n5*wr0[5] + n6*wr0[6] + n7*wr0[7] + n8*wr0[8];
        acc1 += n0*wr1[0] + n1*wr1[1] + n2*wr1[2] + n3*wr1[3] + n4*wr1[4]
              + n5*wr1[5] + n6*wr1[6] + n7*wr1[7] + n8*wr1[8];
        acc2 += n0*wr2[0] + n1*wr2[1] + n2*wr2[2] + n3*wr2[3] + n4*wr2[4]
              + n5*wr2[5] + n6*wr2[6] + n7*wr2[7] + n8*wr2[8];
        acc3 += n0*wr3[0] + n1*wr3[1] + n2*wr3[2] + n3*wr3[3] + n4*wr3[4]
              + n5*wr3[5] + n6*wr3[6] + n7*wr3[7] + n8*wr3[8];
        __syncthreads();
    }

    float4 r;
    {
        const float sc = gma[o0+0] / sqrtf(var[o0+0] + 1e-5f);
        float v = (acc0 + b1[o0+0] - mu[o0+0]) * sc + bta[o0+0];
        r.x = v > 0.f ? v : 0.f;
    }
    {
        const float sc = gma[o0+1] / sqrtf(var[o0+1] + 1e-5f);
        float v = (acc1 + b1[o0+1] - mu[o0+1]) * sc + bta[o0+1];
        r.y = v > 0.f ? v : 0.f;
    }
    {
        const float sc = gma[o0+2] / sqrtf(var[o0+2] + 1e-5f);
        float v = (acc2 + b1[o0+2] - mu[o0+2]) * sc + bta[o0+2];
        r.z = v > 0.f ? v : 0.f;
    }
    {
        const float sc = gma[o0+3] / sqrtf(var[o0+3] + 1e-5f);
        float v = (acc3 + b1[o0+3] - mu[o0+3]) * sc + bta[o0+3];
        r.w = v > 0.f ? v : 0.f;
    }
    *(float4*)&h_t[((size_t)(bn * PIX + tid)) * C_ + o0] = r;
}

// ---------------------------------------------------------------------------
// Kernel D: 4 pillars per block: 1x1 conv -> softmax -> geometry (double) ->
// weight + cell id per point, bump per-cell counter.
// ---------------------------------------------------------------------------
__global__ __launch_bounds__(256) void k_depth(const float* __restrict__ h_t,
                                               const float* __restrict__ w2t,
                                               const float* __restrict__ b2,
                                               const float* __restrict__ intr,
                                               const float* __restrict__ extr,
                                               float* __restrict__ wgt,
                                               int* __restrict__ cellid,
                                               u32* __restrict__ counts) {
    const int wv = threadIdx.x >> 6;
    const int d  = threadIdx.x & 63;
    const int pillar = blockIdx.x * 4 + wv;
    const int bn = pillar / PIX;
    const int p  = pillar % PIX;
    const int b  = bn / N_;
    const int n  = bn % N_;
    const int yi = p / FW_;
    const int xi = p % FW_;

    __shared__ float hs[4][C_];
    hs[wv][d] = h_t[(size_t)pillar * C_ + d];
    __syncthreads();

    float logit = b2[d];
#pragma unroll
    for (int c = 0; c < C_; ++c) logit += hs[wv][c] * w2t[c * D_ + d];

    float m = logit;
#pragma unroll
    for (int off = 32; off; off >>= 1) m = fmaxf(m, __shfl_xor(m, off));
    float e = expf(logit - m);
    float s = e;
#pragma unroll
    for (int off = 32; off; off >>= 1) s += __shfl_xor(s, off);
    const float depth = e / s;

    const double dd = 1.0 + (double)d * (59.0 / 63.0);
    const double px = ((double)xi * (703.0 / 43.0)) * dd;
    const double py = ((double)yi * 17.0) * dd;

    const float* K = &intr[(b * N_ + n) * 9];
    const double a00 = K[0], a01 = K[1], a02 = K[2];
    const double a10 = K[3], a11 = K[4], a12 = K[5];
    const double a20 = K[6], a21 = K[7], a22 = K[8];
    const double det = a00 * (a11 * a22 - a12 * a21)
                     - a01 * (a10 * a22 - a12 * a20)
                     + a02 * (a10 * a21 - a11 * a20);
    const double id = 1.0 / det;
    const double i00 = (a11 * a22 - a12 * a21) * id;
    const double i01 = (a02 * a21 - a01 * a22) * id;
    const double i02 = (a01 * a12 - a02 * a11) * id;
    const double i10 = (a12 * a20 - a10 * a22) * id;
    const double i11 = (a00 * a22 - a02 * a20) * id;
    const double i12 = (a02 * a10 - a00 * a12) * id;
    const double i20 = (a10 * a21 - a11 * a20) * id;
    const double i21 = (a01 * a20 - a00 * a21) * id;
    const double i22 = (a00 * a11 - a01 * a10) * id;

    const double cx = i00 * px + i01 * py + i02 * dd;
    const double cy = i10 * px + i11 * py + i12 * dd;
    const double cz = i20 * px + i21 * py + i22 * dd;

    const float* E = &extr[(b * N_ + n) * 16];
    const double ex = (double)E[0] * cx + (double)E[1] * cy + (double)E[2] * cz + (double)E[3];
    const double ey = (double)E[4] * cx + (double)E[5] * cy + (double)E[6] * cz + (double)E[7];

    const double sx = (ex + 51.2) / 102.4 * 128.0;
    const double sy = (ey + 51.2) / 102.4 * 128.0;
    const int ix = (int)floor(sx);
    const int iy = (int)floor(sy);
    const bool valid = (ix >= 0) && (ix < BEVW) && (iy >= 0) && (iy < BEVH);

    const int i = pillar * D_ + d;
    wgt[i] = depth;
    if (valid) {
        const int cell = b * BEVC + iy * BEVW + ix;
        cellid[i] = cell;
        atomicAdd(&counts[cell], 1u);
    } else {
        cellid[i] = -1;
    }
}

// ---------------------------------------------------------------------------
// Kernel S: single-block scan, 32 cells/thread in registers.
// ---------------------------------------------------------------------------
__global__ __launch_bounds__(1024) void k_scan(u32* __restrict__ counts,
                                               u32* __restrict__ offsets) {
    const int tid  = threadIdx.x;
    const int lane = tid & 63;
    const int wid  = tid >> 6;
    const int base = tid * 32;

    u32 v[32];
    u32 run = 0;
#pragma unroll
    for (int k = 0; k < 32; ++k) {
        u32 t = counts[base + k];
        v[k] = run;
        run += t;
    }

    u32 incl = run;
#pragma unroll
    for (int off = 1; off < 64; off <<= 1) {
        u32 t = __shfl_up(incl, off);
        if (lane >= off) incl += t;
    }
    const u32 wexcl = incl - run;

    __shared__ u32 wtot[16], web[16];
    if (lane == 63) wtot[wid] = incl;
    __syncthreads();
    if (tid == 0) {
        u32 s = 0;
        for (int j = 0; j < 16; ++j) { u32 t = wtot[j]; web[j] = s; s += t; }
    }
    __syncthreads();
    const u32 tbase = web[wid] + wexcl;

#pragma unroll
    for (int k = 0; k < 32; ++k) {
        offsets[base + k] = tbase + v[k];
        counts[base + k] = 0;
    }
    if (tid == 1023) offsets[NCELL] = tbase + run;
}

// ---------------------------------------------------------------------------
// Kernel P: counting-sort placement.
// ---------------------------------------------------------------------------
__global__ void k_place(const int* __restrict__ cellid,
                        const u32* __restrict__ offsets,
                        u32* __restrict__ counts,
                        u32* __restrict__ sorted) {
    const int i = blockIdx.x * 256 + threadIdx.x;
    if (i >= NPOINT) return;
    const int c = cellid[i];
    if (c >= 0) {
        const u32 pos = offsets[c] + atomicAdd(&counts[c], 1u);
        sorted[pos] = (u32)i;
    }
}

// ---------------------------------------------------------------------------
// Kernel G: balanced segment pool. One wave per 64-point segment of the
// sorted list; lane = channel. Metadata pre-loaded per-lane, broadcast via
// shfl; x_t row prefetched 1 ahead. Runs flushed with plain stores when
// segment-exclusive, atomicAdd only for boundary-spanning runs.
// ---------------------------------------------------------------------------
__global__ __launch_bounds__(256) void k_pool(const u32* __restrict__ sorted,
                                              const u32* __restrict__ offsets,
                                              const int* __restrict__ cellid,
                                              const float* __restrict__ wgt,
                                              const float* __restrict__ x_t,
                                              float* __restrict__ out) {
    const u32 P = offsets[NCELL];
    const int wv   = threadIdx.x >> 6;
    const int lane = threadIdx.x & 63;
    const u32 seg  = (u32)blockIdx.x * 4u + (u32)wv;
    const u32 j0   = seg * 64u;
    if (j0 >= P) return;
    const int len = (int)min(64u, P - j0);

    int myidx = 0, mycell = -1; float myw = 0.f;
    if (lane < len) {
        myidx  = (int)sorted[j0 + (u32)lane];
        mycell = cellid[myidx];
        myw    = wgt[myidx];
    }
    const int prev_cell = (j0 > 0) ? cellid[sorted[j0 - 1]] : -2;
    const int next_cell = (j0 + 64 < P) ? cellid[sorted[j0 + 64]] : -2;

    float acc = 0.f;
    int cur = __shfl(mycell, 0);
    bool first = true;

    int idx0 = __shfl(myidx, 0);
    float xrow = x_t[(size_t)(idx0 >> 6) * C_ + lane];

    for (int t = 0; t < len; ++t) {
        const float w = __shfl(myw, t);
        const float xcur = xrow;
        const bool is_last = (t == len - 1);
        if (!is_last) {
            const int idxn = __shfl(myidx, t + 1);
            xrow = x_t[(size_t)(idxn >> 6) * C_ + lane];
        }
        acc += w * xcur;

        const int nxt = is_last ? next_cell : __shfl(mycell, t + 1);
        if (nxt != cur) {
            const bool shared = first && (cur == prev_cell);
            float* dst = out + ((size_t)(cur >> 14) * C_ + lane) * BEVC + (cur & (BEVC - 1));
            if (shared) atomicAdd(dst, acc); else *dst = acc;
            acc = 0.f; first = false; cur = nxt;
        } else if (is_last) {
            // run continues into the next segment -> must combine atomically
            float* dst = out + ((size_t)(cur >> 14) * C_ + lane) * BEVC + (cur & (BEVC - 1));
            atomicAdd(dst, acc);
        }
    }
}

// ---------------------------------------------------------------------------
extern "C" void kernel_launch(void* const* d_in, const int* in_sizes, int n_in,
                              void* d_out, int out_size, void* d_ws, size_t ws_size,
                              hipStream_t stream) {
    const float* feat  = (const float*)d_in[0];
    const float* intr  = (const float*)d_in[1];
    const float* extr  = (const float*)d_in[2];
    const float* w1    = (const float*)d_in[3];
    const float* b1    = (const float*)d_in[4];
    const float* gma   = (const float*)d_in[5];
    const float* bta   = (const float*)d_in[6];
    const float* mu    = (const float*)d_in[7];
    const float* var   = (const float*)d_in[8];
    const float* w2    = (const float*)d_in[9];
    const float* b2    = (const float*)d_in[10];
    float* out = (float*)d_out;

    // workspace layout (all 4B elements)
    float* h_t    = (float*)d_ws;                       // NPOINT
    float* x_t    = h_t + NPOINT;                       // NPOINT
    float* w2t    = x_t + NPOINT;                       // 4096
    float* wgt    = w2t + 4096;                         // NPOINT
    int*   cellid = (int*)(wgt + NPOINT);               // NPOINT
    u32*   counts = (u32*)(cellid + NPOINT);            // NCELL
    u32*   offs   = counts + NCELL;                     // NCELL+1
    u32*   sorted = offs + NCELL + 1;                   // NPOINT

    hipMemsetAsync(d_out, 0, (size_t)out_size * sizeof(float), stream);

    k_transpose<<<BNI * 11, 256, 0, stream>>>(feat, x_t, w2, w2t, counts);
    k_conv1<<<BNI * 16, 704, 0, stream>>>(feat, w1, b1, gma, bta, mu, var, h_t);
    k_depth<<<NPILLAR / 4, 256, 0, stream>>>(h_t, w2t, b2, intr, extr, wgt, cellid, counts);
    k_scan<<<1, 1024, 0, stream>>>(counts, offs);
    k_place<<<(NPOINT + 255) / 256, 256, 0, stream>>>(cellid, offs, counts, sorted);
    k_pool<<<(NPILLAR + 3) / 4, 256, 0, stream>>>(sorted, offs, cellid, wgt, x_t, out);

    (void)in_sizes; (void)n_in; (void)ws_size;
}

// Round 5
// 122.454 us; speedup vs baseline: 10.1986x; 1.3243x over previous
//
#include <hip/hip_runtime.h>
#include <hip/hip_bf16.h>
#include <math.h>

// Problem constants
#define B_  2
#define N_  6
#define C_  64
#define FH_ 16
#define FW_ 44
#define D_  64
#define PIX (FH_*FW_)          // 704
#define BNI (B_*N_)            // 12
#define NPILLAR (BNI*PIX)      // 8448
#define NPOINT (NPILLAR*D_)    // 540672
#define BEVH 128
#define BEVW 128
#define BEVC (BEVH*BEVW)       // 16384
#define NCELL (B_*BEVC)        // 32768
#define PW 46                  // padded plane width
#define PP (18*PW)             // padded plane size = 828

typedef unsigned int u32;

__device__ __forceinline__ int rlane_i(int v, int l) {
    return __builtin_amdgcn_readlane(v, l);
}
__device__ __forceinline__ float rlane_f(float v, int l) {
    return __int_as_float(__builtin_amdgcn_readlane(__float_as_int(v), l));
}

// ---------------------------------------------------------------------------
// Kernel T: LDS-tiled transpose feat -> x_t, w2 transpose, zero counters,
// and (block 132) per-(b,n) fused M = R * inv(K) in double.
// Grid: 133 blocks.
// ---------------------------------------------------------------------------
__global__ __launch_bounds__(256) void k_transpose(const float* __restrict__ feat,
                                                   float* __restrict__ x_t,
                                                   const float* __restrict__ w2,
                                                   float* __restrict__ w2t,
                                                   u32* __restrict__ counts,
                                                   const float* __restrict__ intr,
                                                   const float* __restrict__ extr,
                                                   double* __restrict__ Mbuf) {
    const int tid = threadIdx.x;
    if (blockIdx.x < 132) {
        const int bn = blockIdx.x / 11;
        const int p0 = (blockIdx.x % 11) * 64;
        const int lane = tid & 63;
        const int row4 = tid >> 6;

        __shared__ float tile[64][65];
#pragma unroll
        for (int k = 0; k < 16; ++k) {
            const int c = k * 4 + row4;
            tile[c][lane] = feat[((size_t)bn * C_ + c) * PIX + p0 + lane];
        }
        __syncthreads();
#pragma unroll
        for (int k = 0; k < 16; ++k) {
            const int r = k * 4 + row4;
            x_t[((size_t)bn * PIX + p0 + r) * C_ + lane] = tile[lane][r];
        }
        if (blockIdx.x == 0) {
#pragma unroll
            for (int k = 0; k < 16; ++k) {
                const int idx = k * 256 + tid;
                const int d = idx >> 6, c = idx & 63;
                w2t[c * D_ + d] = w2[idx];
            }
        }
    } else if (tid < BNI) {
        // fused M = R * inv(K), double precision (adjugate inverse)
        const float* K = &intr[tid * 9];
        const double a00 = K[0], a01 = K[1], a02 = K[2];
        const double a10 = K[3], a11 = K[4], a12 = K[5];
        const double a20 = K[6], a21 = K[7], a22 = K[8];
        const double det = a00 * (a11 * a22 - a12 * a21)
                         - a01 * (a10 * a22 - a12 * a20)
                         + a02 * (a10 * a21 - a11 * a20);
        const double id = 1.0 / det;
        double inv[9];
        inv[0] = (a11 * a22 - a12 * a21) * id;
        inv[1] = (a02 * a21 - a01 * a22) * id;
        inv[2] = (a01 * a12 - a02 * a11) * id;
        inv[3] = (a12 * a20 - a10 * a22) * id;
        inv[4] = (a00 * a22 - a02 * a20) * id;
        inv[5] = (a02 * a10 - a00 * a12) * id;
        inv[6] = (a10 * a21 - a11 * a20) * id;
        inv[7] = (a01 * a20 - a00 * a21) * id;
        inv[8] = (a00 * a11 - a01 * a10) * id;
        const float* E = &extr[tid * 16];
        double* M = &Mbuf[tid * 9];
        // R rows are E[0..2], E[4..6], E[8..10]
        for (int r = 0; r < 3; ++r) {
            const double r0 = E[r * 4 + 0], r1 = E[r * 4 + 1], r2 = E[r * 4 + 2];
            M[r * 3 + 0] = r0 * inv[0] + r1 * inv[3] + r2 * inv[6];
            M[r * 3 + 1] = r0 * inv[1] + r1 * inv[4] + r2 * inv[7];
            M[r * 3 + 2] = r0 * inv[2] + r1 * inv[5] + r2 * inv[8];
        }
    }
    const int gz = blockIdx.x * 256 + tid;
    if (gz < NCELL) counts[gz] = 0;
}

// ---------------------------------------------------------------------------
// Kernel A: conv1 (3x3 SAME), input-channel-split x2. Raw partial sums only
// (bias/BN/ReLU folded into k_depth). Grid: 384 = bn(12) x og(16) x chunk(2).
// ---------------------------------------------------------------------------
__global__ __launch_bounds__(704) void k_conv1(const float* __restrict__ feat,
                                               const float* __restrict__ w1,
                                               float* __restrict__ hp0,
                                               float* __restrict__ hp1) {
    const int blk = blockIdx.x;
    const int bn  = blk >> 5;
    const int o0  = (blk & 15) * 4;
    const int ch  = (blk >> 4) & 1;
    const int c0  = ch * 32;
    const int tid = threadIdx.x;           // pixel 0..703
    const int y   = tid / FW_;
    const int x   = tid % FW_;
    const int wpos = (y + 1) * PW + (x + 1);
    const int rpos = y * PW + x;

    __shared__ float xp[2][PP];
    for (int t = tid; t < 2 * PP; t += 704) ((float*)xp)[t] = 0.0f;

    const float* fbase = feat + ((size_t)bn * C_ + c0) * PIX + tid;
    float vload = fbase[0];
    __syncthreads();
    xp[0][wpos] = vload;
    vload = fbase[PIX];
    __syncthreads();

    float acc0 = 0.f, acc1 = 0.f, acc2 = 0.f, acc3 = 0.f;

#pragma unroll 2
    for (int i = 0; i < 32; ++i) {
        const int cb = i & 1;
        if (i < 31) xp[cb ^ 1][wpos] = vload;
        if (i < 30) vload = fbase[(i + 2) * PIX];

        const float* bb = &xp[cb][rpos];
        const float n0 = bb[0],      n1 = bb[1],      n2 = bb[2];
        const float n3 = bb[PW],     n4 = bb[PW+1],   n5 = bb[PW+2];
        const float n6 = bb[2*PW],   n7 = bb[2*PW+1], n8 = bb[2*PW+2];

        const float* wr0 = w1 + ((size_t)(o0 + 0) * C_ + c0 + i) * 9;
        const float* wr1 = w1 + ((size_t)(o0 + 1) * C_ + c0 + i) * 9;
        const float* wr2 = w1 + ((size_t)(o0 + 2) * C_ + c0 + i) * 9;
        const float* wr3 = w1 + ((size_t)(o0 + 3) * C_ + c0 + i) * 9;
        acc0 += n0*wr0[0] + n1*wr0[1] + n2*wr0[2] + n3*wr0[3] + n4*wr0[4]
              + n5*wr0[5] + n6*wr0[6] + n7*wr0[7] + n8*wr0[8];
        acc1 += n0*wr1[0] + n1*wr1[1] + n2*wr1[2] + n3*wr1[3] + n4*wr1[4]
              + n5*wr1[5] + n6*wr1[6] + n7*wr1[7] + n8*wr1[8];
        acc2 += n0*wr2[0] + n1*wr2[1] + n2*wr2[2] + n3*wr2[3] + n4*wr2[4]
              + n5*wr2[5] + n6*wr2[6] + n7*wr2[7] + n8*wr2[8];
        acc3 += n0*wr3[0] + n1*wr3[1] + n2*wr3[2] + n3*wr3[3] + n4*wr3[4]
              + n5*wr3[5] + n6*wr3[6] + n7*wr3[7] + n8*wr3[8];
        __syncthreads();
    }

    float4 r; r.x = acc0; r.y = acc1; r.z = acc2; r.w = acc3;
    float* hp = ch ? hp1 : hp0;
    *(float4*)&hp[((size_t)(bn * PIX + tid)) * C_ + o0] = r;
}

// ---------------------------------------------------------------------------
// Kernel D: sum partials + bias + BN + ReLU -> 1x1 conv -> softmax ->
// simplified geometry (ego = d*v + t, v = M*(x,y,1)) -> wgt, packed
// (rank<<15 | cell) via atomic rank.
// ---------------------------------------------------------------------------
__global__ __launch_bounds__(256) void k_depth(const float* __restrict__ hp0,
                                               const float* __restrict__ hp1,
                                               const float* __restrict__ b1,
                                               const float* __restrict__ gma,
                                               const float* __restrict__ bta,
                                               const float* __restrict__ mu,
                                               const float* __restrict__ var,
                                               const float* __restrict__ w2t,
                                               const float* __restrict__ b2,
                                               const double* __restrict__ Mbuf,
                                               const float* __restrict__ extr,
                                               float* __restrict__ wgt,
                                               u32* __restrict__ cellinfo,
                                               u32* __restrict__ counts) {
    const int wv = threadIdx.x >> 6;
    const int d  = threadIdx.x & 63;
    const int pillar = blockIdx.x * 4 + wv;
    const int bn = pillar / PIX;
    const int p  = pillar % PIX;
    const int yi = p / FW_;
    const int xi = p % FW_;

    __shared__ float hs[4][C_];
    {
        const size_t o = (size_t)pillar * C_ + d;
        float h = hp0[o] + hp1[o] + b1[d];
        const float sc = gma[d] / sqrtf(var[d] + 1e-5f);
        h = (h - mu[d]) * sc + bta[d];
        hs[wv][d] = h > 0.f ? h : 0.f;
    }
    __syncthreads();

    float logit = b2[d];
#pragma unroll
    for (int c = 0; c < C_; ++c) logit += hs[wv][c] * w2t[c * D_ + d];

    float m = logit;
#pragma unroll
    for (int off = 32; off; off >>= 1) m = fmaxf(m, __shfl_xor(m, off));
    float e = expf(logit - m);
    float s = e;
#pragma unroll
    for (int off = 32; off; off >>= 1) s += __shfl_xor(s, off);

    // geometry: ego = d * (M*(x,y,1)) + t
    const double* M = &Mbuf[bn * 9];
    const double xn = (double)xi * (703.0 / 43.0);
    const double yn = (double)yi * 17.0;
    const double vx = M[0] * xn + M[1] * yn + M[2];
    const double vy = M[3] * xn + M[4] * yn + M[5];
    const double dd = 1.0 + (double)d * (59.0 / 63.0);
    const float* E = &extr[bn * 16];
    const double ex = dd * vx + (double)E[3];
    const double ey = dd * vy + (double)E[7];
    const int ix = (int)floor((ex + 51.2) * 1.25);
    const int iy = (int)floor((ey + 51.2) * 1.25);
    const bool valid = (ix >= 0) && (ix < BEVW) && (iy >= 0) && (iy < BEVH);

    const int i = pillar * D_ + d;
    wgt[i] = e / s;
    if (valid) {
        const int cell = (bn / N_) * BEVC + iy * BEVW + ix;
        const u32 rank = atomicAdd(&counts[cell], 1u);
        cellinfo[i] = (rank << 15) | (u32)cell;
    } else {
        cellinfo[i] = 0xFFFFFFFFu;
    }
}

// ---------------------------------------------------------------------------
// Kernel S: single-block scan (32 cells/thread in registers); writes padding
// sentinels after the last valid point.
// ---------------------------------------------------------------------------
__global__ __launch_bounds__(1024) void k_scan(const u32* __restrict__ counts,
                                               u32* __restrict__ offsets,
                                               float* __restrict__ sorted_w,
                                               u32* __restrict__ sorted_meta) {
    const int tid  = threadIdx.x;
    const int lane = tid & 63;
    const int wid  = tid >> 6;
    const int base = tid * 32;

    u32 v[32];
    u32 run = 0;
#pragma unroll
    for (int k = 0; k < 32; ++k) {
        u32 t = counts[base + k];
        v[k] = run;
        run += t;
    }

    u32 incl = run;
#pragma unroll
    for (int off = 1; off < 64; off <<= 1) {
        u32 t = __shfl_up(incl, off);
        if (lane >= off) incl += t;
    }
    const u32 wexcl = incl - run;

    __shared__ u32 wtot[16], web[16];
    if (lane == 63) wtot[wid] = incl;
    __syncthreads();
    if (tid == 0) {
        u32 s = 0;
        for (int j = 0; j < 16; ++j) { u32 t = wtot[j]; web[j] = s; s += t; }
    }
    __syncthreads();
    const u32 tbase = web[wid] + wexcl;

#pragma unroll
    for (int k = 0; k < 32; ++k) offsets[base + k] = tbase + v[k];

    const u32 total = web[15] + wtot[15];
    if (tid == 1023) offsets[NCELL] = total;
    if (tid < 128) {
        sorted_w[total + tid] = 0.0f;
        sorted_meta[total + tid] = (32767u << 14);   // dummy: last cell, w=0
    }
}

// ---------------------------------------------------------------------------
// Kernel P: atomic-free placement using ranks from k_depth.
// ---------------------------------------------------------------------------
__global__ void k_place(const u32* __restrict__ cellinfo,
                        const float* __restrict__ wgt,
                        const u32* __restrict__ offsets,
                        float* __restrict__ sorted_w,
                        u32* __restrict__ sorted_meta) {
    const int i = blockIdx.x * 256 + threadIdx.x;
    if (i >= NPOINT) return;
    const u32 ci = cellinfo[i];
    if (ci != 0xFFFFFFFFu) {
        const u32 cell = ci & 0x7FFFu;
        const u32 rank = ci >> 15;
        const u32 pos  = offsets[cell] + rank;
        sorted_w[pos]    = wgt[i];
        sorted_meta[pos] = (cell << 14) | (u32)(i >> 6);   // cell | pillar
    }
}

// ---------------------------------------------------------------------------
// Kernel G: balanced segment pool. One wave per 64-point segment; lane =
// channel. readlane (scalar) broadcasts -> uniform flush branches; 4-deep
// x_t row prefetch. Dummy padding keeps every wave at exactly 64 iters.
// ---------------------------------------------------------------------------
__global__ __launch_bounds__(256) void k_pool(const float* __restrict__ sorted_w,
                                              const u32* __restrict__ sorted_meta,
                                              const u32* __restrict__ offsets,
                                              const float* __restrict__ x_t,
                                              float* __restrict__ out) {
    const u32 P = offsets[NCELL];
    const int wv   = threadIdx.x >> 6;
    const int lane = threadIdx.x & 63;
    const u32 j0   = ((u32)blockIdx.x * 4u + (u32)wv) * 64u;
    if (j0 >= P) return;

    const u32 meta = sorted_meta[j0 + (u32)lane];
    const float myw = sorted_w[j0 + (u32)lane];
    const int mycell = (int)(meta >> 14);
    const int mypil  = (int)(meta & 0x3FFFu);

    const int prev_cell = (j0 > 0) ? (int)(sorted_meta[j0 - 1] >> 14) : -1;
    const int next_cell = (int)(sorted_meta[j0 + 64] >> 14);

    float acc = 0.f;
    int cur = rlane_i(mycell, 0);
    bool first = true;

    float xr0 = x_t[(size_t)rlane_i(mypil, 0) * C_ + lane];
    float xr1 = x_t[(size_t)rlane_i(mypil, 1) * C_ + lane];
    float xr2 = x_t[(size_t)rlane_i(mypil, 2) * C_ + lane];
    float xr3 = x_t[(size_t)rlane_i(mypil, 3) * C_ + lane];

#define DST(cc) (out + ((size_t)((cc) >> 14) * C_ + lane) * BEVC + ((cc) & (BEVC - 1)))
#define POOL_STEP(tt, xr)                                                     \
    {                                                                         \
        const float wb = rlane_f(myw, (tt));                                  \
        acc += wb * (xr);                                                     \
        const int nxt = ((tt) == 63) ? next_cell : rlane_i(mycell, (tt) + 1); \
        if ((tt) == 63 && nxt == cur) {                                       \
            atomicAdd(DST(cur), acc);                                         \
        } else if (nxt != cur) {                                              \
            if (first && cur == prev_cell) atomicAdd(DST(cur), acc);          \
            else *DST(cur) = acc;                                             \
            acc = 0.f; first = false; cur = nxt;                              \
        }                                                                     \
    }

#pragma unroll
    for (int t4 = 0; t4 < 16; ++t4) {
        const int t = t4 * 4;
        float y0 = 0.f, y1 = 0.f, y2 = 0.f, y3 = 0.f;
        if (t4 < 15) {
            const int q0 = rlane_i(mypil, t + 4);
            const int q1 = rlane_i(mypil, t + 5);
            const int q2 = rlane_i(mypil, t + 6);
            const int q3 = rlane_i(mypil, t + 7);
            y0 = x_t[(size_t)q0 * C_ + lane];
            y1 = x_t[(size_t)q1 * C_ + lane];
            y2 = x_t[(size_t)q2 * C_ + lane];
            y3 = x_t[(size_t)q3 * C_ + lane];
        }
        POOL_STEP(t + 0, xr0);
        POOL_STEP(t + 1, xr1);
        POOL_STEP(t + 2, xr2);
        POOL_STEP(t + 3, xr3);
        xr0 = y0; xr1 = y1; xr2 = y2; xr3 = y3;
    }
#undef POOL_STEP
#undef DST
}

// ---------------------------------------------------------------------------
extern "C" void kernel_launch(void* const* d_in, const int* in_sizes, int n_in,
                              void* d_out, int out_size, void* d_ws, size_t ws_size,
                              hipStream_t stream) {
    const float* feat  = (const float*)d_in[0];
    const float* intr  = (const float*)d_in[1];
    const float* extr  = (const float*)d_in[2];
    const float* w1    = (const float*)d_in[3];
    const float* b1    = (const float*)d_in[4];
    const float* gma   = (const float*)d_in[5];
    const float* bta   = (const float*)d_in[6];
    const float* mu    = (const float*)d_in[7];
    const float* var   = (const float*)d_in[8];
    const float* w2    = (const float*)d_in[9];
    const float* b2    = (const float*)d_in[10];
    float* out = (float*)d_out;

    // workspace layout: doubles first (alignment), then 4B arrays
    double* Mbuf  = (double*)d_ws;                      // 108 doubles (12*9)
    float*  base  = (float*)d_ws + 256;                 // 1 KiB offset
    float*  x_t   = base;                               // NPOINT
    float*  hp0   = x_t + NPOINT;                       // NPOINT+128 (= sorted_w)
    float*  hp1   = hp0 + NPOINT + 128;                 // NPOINT+128 (= sorted_meta)
    float*  wgt   = hp1 + NPOINT + 128;                 // NPOINT
    u32*    cinfo = (u32*)(wgt + NPOINT);               // NPOINT
    u32*    counts= cinfo + NPOINT;                     // NCELL
    u32*    offs  = counts + NCELL;                     // NCELL+1
    float*  w2t   = (float*)(offs + NCELL + 1);         // 4096

    float* sorted_w    = hp0;          // overlay (h-partials dead after k_depth)
    u32*   sorted_meta = (u32*)hp1;

    hipMemsetAsync(d_out, 0, (size_t)out_size * sizeof(float), stream);

    k_transpose<<<133, 256, 0, stream>>>(feat, x_t, w2, w2t, counts, intr, extr, Mbuf);
    k_conv1<<<BNI * 32, 704, 0, stream>>>(feat, w1, hp0, hp1);
    k_depth<<<NPILLAR / 4, 256, 0, stream>>>(hp0, hp1, b1, gma, bta, mu, var,
                                             w2t, b2, Mbuf, extr, wgt, cinfo, counts);
    k_scan<<<1, 1024, 0, stream>>>(counts, offs, sorted_w, sorted_meta);
    k_place<<<(NPOINT + 255) / 256, 256, 0, stream>>>(cinfo, wgt, offs, sorted_w, sorted_meta);
    k_pool<<<NPOINT / 64 / 4, 256, 0, stream>>>(sorted_w, sorted_meta, offs, x_t, out);

    (void)in_sizes; (void)n_in; (void)ws_size;
}

// Round 6
// 120.069 us; speedup vs baseline: 10.4012x; 1.0199x over previous
//
#include <hip/hip_runtime.h>
#include <hip/hip_bf16.h>
#include <math.h>

// Problem constants
#define B_  2
#define N_  6
#define C_  64
#define FH_ 16
#define FW_ 44
#define D_  64
#define PIX (FH_*FW_)          // 704
#define BNI (B_*N_)            // 12
#define NPILLAR (BNI*PIX)      // 8448
#define NPOINT (NPILLAR*D_)    // 540672
#define BEVH 128
#define BEVW 128
#define BEVC (BEVH*BEVW)       // 16384
#define NCELL (B_*BEVC)        // 32768
#define PW 46                  // padded plane width
#define PP (18*PW)             // padded plane size = 828

typedef unsigned int u32;

__device__ __forceinline__ int rlane_i(int v, int l) {
    return __builtin_amdgcn_readlane(v, l);
}
__device__ __forceinline__ float rlane_f(float v, int l) {
    return __int_as_float(__builtin_amdgcn_readlane(__float_as_int(v), l));
}

// ---------------------------------------------------------------------------
// Kernel T: LDS-tiled transpose feat -> x_t, w2 transpose, zero counters,
// per-(b,n) fused M = R*inv(K) in double (block 132). Grid: 133 blocks.
// ---------------------------------------------------------------------------
__global__ __launch_bounds__(256) void k_transpose(const float* __restrict__ feat,
                                                   float* __restrict__ x_t,
                                                   const float* __restrict__ w2,
                                                   float* __restrict__ w2t,
                                                   u32* __restrict__ counts,
                                                   const float* __restrict__ intr,
                                                   const float* __restrict__ extr,
                                                   double* __restrict__ Mbuf) {
    const int tid = threadIdx.x;
    if (blockIdx.x < 132) {
        const int bn = blockIdx.x / 11;
        const int p0 = (blockIdx.x % 11) * 64;
        const int lane = tid & 63;
        const int row4 = tid >> 6;

        __shared__ float tile[64][65];
#pragma unroll
        for (int k = 0; k < 16; ++k) {
            const int c = k * 4 + row4;
            tile[c][lane] = feat[((size_t)bn * C_ + c) * PIX + p0 + lane];
        }
        __syncthreads();
#pragma unroll
        for (int k = 0; k < 16; ++k) {
            const int r = k * 4 + row4;
            x_t[((size_t)bn * PIX + p0 + r) * C_ + lane] = tile[lane][r];
        }
        if (blockIdx.x == 0) {
#pragma unroll
            for (int k = 0; k < 16; ++k) {
                const int idx = k * 256 + tid;
                const int d = idx >> 6, c = idx & 63;
                w2t[c * D_ + d] = w2[idx];
            }
        }
    } else if (tid < BNI) {
        const float* K = &intr[tid * 9];
        const double a00 = K[0], a01 = K[1], a02 = K[2];
        const double a10 = K[3], a11 = K[4], a12 = K[5];
        const double a20 = K[6], a21 = K[7], a22 = K[8];
        const double det = a00 * (a11 * a22 - a12 * a21)
                         - a01 * (a10 * a22 - a12 * a20)
                         + a02 * (a10 * a21 - a11 * a20);
        const double id = 1.0 / det;
        double inv[9];
        inv[0] = (a11 * a22 - a12 * a21) * id;
        inv[1] = (a02 * a21 - a01 * a22) * id;
        inv[2] = (a01 * a12 - a02 * a11) * id;
        inv[3] = (a12 * a20 - a10 * a22) * id;
        inv[4] = (a00 * a22 - a02 * a20) * id;
        inv[5] = (a02 * a10 - a00 * a12) * id;
        inv[6] = (a10 * a21 - a11 * a20) * id;
        inv[7] = (a01 * a20 - a00 * a21) * id;
        inv[8] = (a00 * a11 - a01 * a10) * id;
        const float* E = &extr[tid * 16];
        double* M = &Mbuf[tid * 9];
        for (int r = 0; r < 3; ++r) {
            const double r0 = E[r * 4 + 0], r1 = E[r * 4 + 1], r2 = E[r * 4 + 2];
            M[r * 3 + 0] = r0 * inv[0] + r1 * inv[3] + r2 * inv[6];
            M[r * 3 + 1] = r0 * inv[1] + r1 * inv[4] + r2 * inv[7];
            M[r * 3 + 2] = r0 * inv[2] + r1 * inv[5] + r2 * inv[8];
        }
    }
    const int gz = blockIdx.x * 256 + tid;
    if (gz < NCELL) counts[gz] = 0;
}

// ---------------------------------------------------------------------------
// Kernel A: conv1 (3x3 SAME), 4-way input-channel split, raw partial sums.
// Grid: 768 = bn(12) x og(16) x chunk(4). Block: 704 = 1 thread/pixel.
// ---------------------------------------------------------------------------
__global__ __launch_bounds__(704) void k_conv1(const float* __restrict__ feat,
                                               const float* __restrict__ w1,
                                               float* __restrict__ hpAll) {
    const int blk = blockIdx.x;
    const int bn  = blk >> 6;
    const int o0  = (blk & 15) * 4;
    const int ch  = (blk >> 4) & 3;
    const int c0  = ch * 16;
    const int tid = threadIdx.x;
    const int y   = tid / FW_;
    const int x   = tid % FW_;
    const int wpos = (y + 1) * PW + (x + 1);
    const int rpos = y * PW + x;

    __shared__ float xp[2][PP];
    for (int t = tid; t < 2 * PP; t += 704) ((float*)xp)[t] = 0.0f;

    const float* fbase = feat + ((size_t)bn * C_ + c0) * PIX + tid;
    float vload = fbase[0];
    __syncthreads();
    xp[0][wpos] = vload;
    vload = fbase[PIX];
    __syncthreads();

    float acc0 = 0.f, acc1 = 0.f, acc2 = 0.f, acc3 = 0.f;

#pragma unroll 2
    for (int i = 0; i < 16; ++i) {
        const int cb = i & 1;
        if (i < 15) xp[cb ^ 1][wpos] = vload;
        if (i < 14) vload = fbase[(i + 2) * PIX];

        const float* bb = &xp[cb][rpos];
        const float n0 = bb[0],      n1 = bb[1],      n2 = bb[2];
        const float n3 = bb[PW],     n4 = bb[PW+1],   n5 = bb[PW+2];
        const float n6 = bb[2*PW],   n7 = bb[2*PW+1], n8 = bb[2*PW+2];

        const float* wr0 = w1 + ((size_t)(o0 + 0) * C_ + c0 + i) * 9;
        const float* wr1 = w1 + ((size_t)(o0 + 1) * C_ + c0 + i) * 9;
        const float* wr2 = w1 + ((size_t)(o0 + 2) * C_ + c0 + i) * 9;
        const float* wr3 = w1 + ((size_t)(o0 + 3) * C_ + c0 + i) * 9;
        acc0 += n0*wr0[0] + n1*wr0[1] + n2*wr0[2] + n3*wr0[3] + n4*wr0[4]
              + n5*wr0[5] + n6*wr0[6] + n7*wr0[7] + n8*wr0[8];
        acc1 += n0*wr1[0] + n1*wr1[1] + n2*wr1[2] + n3*wr1[3] + n4*wr1[4]
              + n5*wr1[5] + n6*wr1[6] + n7*wr1[7] + n8*wr1[8];
        acc2 += n0*wr2[0] + n1*wr2[1] + n2*wr2[2] + n3*wr2[3] + n4*wr2[4]
              + n5*wr2[5] + n6*wr2[6] + n7*wr2[7] + n8*wr2[8];
        acc3 += n0*wr3[0] + n1*wr3[1] + n2*wr3[2] + n3*wr3[3] + n4*wr3[4]
              + n5*wr3[5] + n6*wr3[6] + n7*wr3[7] + n8*wr3[8];
        __syncthreads();
    }

    float4 r; r.x = acc0; r.y = acc1; r.z = acc2; r.w = acc3;
    *(float4*)&hpAll[(size_t)ch * NPOINT + ((size_t)(bn * PIX + tid)) * C_ + o0] = r;
}

// ---------------------------------------------------------------------------
// Kernel D: sum 4 partials + bias + BN + ReLU -> 1x1 conv -> softmax ->
// geometry (ego = d*v + t) -> packed point record {w, rank<<15|cell}.
// ---------------------------------------------------------------------------
__global__ __launch_bounds__(256) void k_depth(const float* __restrict__ hpAll,
                                               const float* __restrict__ b1,
                                               const float* __restrict__ gma,
                                               const float* __restrict__ bta,
                                               const float* __restrict__ mu,
                                               const float* __restrict__ var,
                                               const float* __restrict__ w2t,
                                               const float* __restrict__ b2,
                                               const double* __restrict__ Mbuf,
                                               const float* __restrict__ extr,
                                               uint2* __restrict__ pc,
                                               u32* __restrict__ counts) {
    const int wv = threadIdx.x >> 6;
    const int d  = threadIdx.x & 63;
    const int pillar = blockIdx.x * 4 + wv;
    const int bn = pillar / PIX;
    const int p  = pillar % PIX;
    const int yi = p / FW_;
    const int xi = p % FW_;

    __shared__ float hs[4][C_];
    {
        const size_t o = (size_t)pillar * C_ + d;
        float h = hpAll[o] + hpAll[NPOINT + o] + hpAll[2 * (size_t)NPOINT + o]
                + hpAll[3 * (size_t)NPOINT + o] + b1[d];
        const float sc = gma[d] / sqrtf(var[d] + 1e-5f);
        h = (h - mu[d]) * sc + bta[d];
        hs[wv][d] = h > 0.f ? h : 0.f;
    }
    __syncthreads();

    float logit = b2[d];
#pragma unroll
    for (int c = 0; c < C_; ++c) logit += hs[wv][c] * w2t[c * D_ + d];

    float m = logit;
#pragma unroll
    for (int off = 32; off; off >>= 1) m = fmaxf(m, __shfl_xor(m, off));
    float e = expf(logit - m);
    float s = e;
#pragma unroll
    for (int off = 32; off; off >>= 1) s += __shfl_xor(s, off);

    // geometry: ego = d * (M*(x,y,1)) + t
    const double* M = &Mbuf[bn * 9];
    const double xn = (double)xi * (703.0 / 43.0);
    const double yn = (double)yi * 17.0;
    const double vx = M[0] * xn + M[1] * yn + M[2];
    const double vy = M[3] * xn + M[4] * yn + M[5];
    const double dd = 1.0 + (double)d * (59.0 / 63.0);
    const float* E = &extr[bn * 16];
    const double ex = dd * vx + (double)E[3];
    const double ey = dd * vy + (double)E[7];
    const int ix = (int)floor((ex + 51.2) * 1.25);
    const int iy = (int)floor((ey + 51.2) * 1.25);
    const bool valid = (ix >= 0) && (ix < BEVW) && (iy >= 0) && (iy < BEVH);

    const int i = pillar * D_ + d;
    uint2 rec;
    rec.x = __float_as_uint(e / s);
    if (valid) {
        const int cell = (bn / N_) * BEVC + iy * BEVW + ix;
        const u32 rank = atomicAdd(&counts[cell], 1u);
        rec.y = (rank << 15) | (u32)cell;
    } else {
        rec.y = 0xFFFFFFFFu;
    }
    pc[i] = rec;
}

// ---------------------------------------------------------------------------
// Kernel S: single-block scan (32 cells/thread); writes dummy sentinels.
// ---------------------------------------------------------------------------
__global__ __launch_bounds__(1024) void k_scan(const u32* __restrict__ counts,
                                               u32* __restrict__ offsets,
                                               uint2* __restrict__ sorted) {
    const int tid  = threadIdx.x;
    const int lane = tid & 63;
    const int wid  = tid >> 6;
    const int base = tid * 32;

    u32 v[32];
    u32 run = 0;
#pragma unroll
    for (int k = 0; k < 32; ++k) {
        u32 t = counts[base + k];
        v[k] = run;
        run += t;
    }

    u32 incl = run;
#pragma unroll
    for (int off = 1; off < 64; off <<= 1) {
        u32 t = __shfl_up(incl, off);
        if (lane >= off) incl += t;
    }
    const u32 wexcl = incl - run;

    __shared__ u32 wtot[16], web[16];
    if (lane == 63) wtot[wid] = incl;
    __syncthreads();
    if (tid == 0) {
        u32 s = 0;
        for (int j = 0; j < 16; ++j) { u32 t = wtot[j]; web[j] = s; s += t; }
    }
    __syncthreads();
    const u32 tbase = web[wid] + wexcl;

#pragma unroll
    for (int k = 0; k < 32; ++k) offsets[base + k] = tbase + v[k];

    const u32 total = web[15] + wtot[15];
    if (tid == 1023) offsets[NCELL] = total;
    if (tid < 128) {
        uint2 dummy; dummy.x = 0u; dummy.y = 0xFFFFFFFFu;  // cell 0x3FFFF >= NCELL
        sorted[total + tid] = dummy;
    }
}

// ---------------------------------------------------------------------------
// Kernel Z: zero only the output cells k_pool won't plain-store:
// empty cells and segment-boundary-spanning cells.
// Grid: 2048 x 256; thread = 4 consecutive cells of one (b,c) plane.
// ---------------------------------------------------------------------------
__global__ __launch_bounds__(256) void k_zero(const u32* __restrict__ offsets,
                                              float* __restrict__ out) {
    const int t  = blockIdx.x * 256 + threadIdx.x;   // < 2*64*4096
    const int c4 = t & 4095;
    const int bc = t >> 12;                          // b*64 + c
    const int b  = bc >> 6;
    const int cellbase = b * BEVC + c4 * 4;

    const uint4 o4 = *(const uint4*)&offsets[cellbase];
    const u32 o4e  = offsets[cellbase + 4];
    float* dst = out + ((size_t)bc * BEVC) + c4 * 4;

    if (o4.x == o4e) {                               // all 4 empty
        *(float4*)dst = make_float4(0.f, 0.f, 0.f, 0.f);
        return;
    }
    const u32 s0 = o4.x, s1 = o4.y, s2 = o4.z, s3 = o4.w, s4 = o4e;
    if (s0 == s1 || (s0 >> 6) != ((s1 - 1) >> 6)) dst[0] = 0.f;
    if (s1 == s2 || (s1 >> 6) != ((s2 - 1) >> 6)) dst[1] = 0.f;
    if (s2 == s3 || (s2 >> 6) != ((s3 - 1) >> 6)) dst[2] = 0.f;
    if (s3 == s4 || (s3 >> 6) != ((s4 - 1) >> 6)) dst[3] = 0.f;
}

// ---------------------------------------------------------------------------
// Kernel P: atomic-free placement using ranks; writes packed uint2.
// ---------------------------------------------------------------------------
__global__ void k_place(const uint2* __restrict__ pc,
                        const u32* __restrict__ offsets,
                        uint2* __restrict__ sorted) {
    const int i = blockIdx.x * 256 + threadIdx.x;
    if (i >= NPOINT) return;
    const uint2 rec = pc[i];
    if (rec.y != 0xFFFFFFFFu) {
        const u32 cell = rec.y & 0x7FFFu;
        const u32 rank = rec.y >> 15;
        const u32 pos  = offsets[cell] + rank;
        uint2 o; o.x = rec.x; o.y = (cell << 14) | (u32)(i >> 6);
        sorted[pos] = o;
    }
}

// ---------------------------------------------------------------------------
// Kernel G: balanced segment pool. One wave per 64-point segment; lane =
// channel; readlane broadcasts; 4-deep x_t prefetch; dummy-guarded flushes.
// ---------------------------------------------------------------------------
__global__ __launch_bounds__(256) void k_pool(const uint2* __restrict__ sorted,
                                              const u32* __restrict__ offsets,
                                              const float* __restrict__ x_t,
                                              float* __restrict__ out) {
    const u32 P = offsets[NCELL];
    const int wv   = threadIdx.x >> 6;
    const int lane = threadIdx.x & 63;
    const u32 j0   = ((u32)blockIdx.x * 4u + (u32)wv) * 64u;
    if (j0 >= P) return;

    const uint2 pr  = sorted[j0 + (u32)lane];
    const float myw = __uint_as_float(pr.x);
    const int mycell = (int)(pr.y >> 14);
    const int mypil  = (int)(pr.y & 0x3FFFu);

    const int prev_cell = (j0 > 0) ? (int)(sorted[j0 - 1].y >> 14) : -1;
    const int next_cell = (int)(sorted[j0 + 64].y >> 14);

    float acc = 0.f;
    int cur = rlane_i(mycell, 0);
    bool first = true;

    float xr0 = x_t[(size_t)rlane_i(mypil, 0) * C_ + lane];
    float xr1 = x_t[(size_t)rlane_i(mypil, 1) * C_ + lane];
    float xr2 = x_t[(size_t)rlane_i(mypil, 2) * C_ + lane];
    float xr3 = x_t[(size_t)rlane_i(mypil, 3) * C_ + lane];

#define DST(cc) (out + ((size_t)((cc) >> 14) * C_ + lane) * BEVC + ((cc) & (BEVC - 1)))
#define POOL_STEP(tt, xr)                                                     \
    {                                                                         \
        const float wb = rlane_f(myw, (tt));                                  \
        acc += wb * (xr);                                                     \
        const int nxt = ((tt) == 63) ? next_cell : rlane_i(mycell, (tt) + 1); \
        if ((tt) == 63 && nxt == cur) {                                       \
            if (cur < NCELL) atomicAdd(DST(cur), acc);                        \
        } else if (nxt != cur) {                                              \
            if (cur < NCELL) {                                                \
                if (first && cur == prev_cell) atomicAdd(DST(cur), acc);      \
                else *DST(cur) = acc;                                         \
            }                                                                 \
            acc = 0.f; first = false; cur = nxt;                              \
        }                                                                     \
    }

#pragma unroll
    for (int t4 = 0; t4 < 16; ++t4) {
        const int t = t4 * 4;
        float y0 = 0.f, y1 = 0.f, y2 = 0.f, y3 = 0.f;
        if (t4 < 15) {
            const int q0 = rlane_i(mypil, t + 4);
            const int q1 = rlane_i(mypil, t + 5);
            const int q2 = rlane_i(mypil, t + 6);
            const int q3 = rlane_i(mypil, t + 7);
            y0 = x_t[(size_t)q0 * C_ + lane];
            y1 = x_t[(size_t)q1 * C_ + lane];
            y2 = x_t[(size_t)q2 * C_ + lane];
            y3 = x_t[(size_t)q3 * C_ + lane];
        }
        POOL_STEP(t + 0, xr0);
        POOL_STEP(t + 1, xr1);
        POOL_STEP(t + 2, xr2);
        POOL_STEP(t + 3, xr3);
        xr0 = y0; xr1 = y1; xr2 = y2; xr3 = y3;
    }
#undef POOL_STEP
#undef DST
}

// ---------------------------------------------------------------------------
extern "C" void kernel_launch(void* const* d_in, const int* in_sizes, int n_in,
                              void* d_out, int out_size, void* d_ws, size_t ws_size,
                              hipStream_t stream) {
    const float* feat  = (const float*)d_in[0];
    const float* intr  = (const float*)d_in[1];
    const float* extr  = (const float*)d_in[2];
    const float* w1    = (const float*)d_in[3];
    const float* b1    = (const float*)d_in[4];
    const float* gma   = (const float*)d_in[5];
    const float* bta   = (const float*)d_in[6];
    const float* mu    = (const float*)d_in[7];
    const float* var   = (const float*)d_in[8];
    const float* w2    = (const float*)d_in[9];
    const float* b2    = (const float*)d_in[10];
    float* out = (float*)d_out;

    // workspace layout (8B-aligned first)
    double* Mbuf   = (double*)d_ws;                                  // 1 KiB
    uint2*  sorted = (uint2*)((char*)d_ws + 1024);                   // NPOINT+128
    uint2*  pc     = sorted + NPOINT + 128;                          // NPOINT
    float*  x_t    = (float*)(pc + NPOINT);                          // NPOINT
    float*  hpAll  = x_t + NPOINT;                                   // 4*NPOINT
    u32*    counts = (u32*)(hpAll + 4 * (size_t)NPOINT);             // NCELL
    u32*    offs   = counts + NCELL;                                 // NCELL+1
    float*  w2t    = (float*)(offs + NCELL + 1);                     // 4096

    k_transpose<<<133, 256, 0, stream>>>(feat, x_t, w2, w2t, counts, intr, extr, Mbuf);
    k_conv1<<<BNI * 64, 704, 0, stream>>>(feat, w1, hpAll);
    k_depth<<<NPILLAR / 4, 256, 0, stream>>>(hpAll, b1, gma, bta, mu, var,
                                             w2t, b2, Mbuf, extr, pc, counts);
    k_scan<<<1, 1024, 0, stream>>>(counts, offs, sorted);
    k_zero<<<2048, 256, 0, stream>>>(offs, out);
    k_place<<<(NPOINT + 255) / 256, 256, 0, stream>>>(pc, offs, sorted);
    k_pool<<<NPOINT / 64 / 4, 256, 0, stream>>>(sorted, offs, x_t, out);

    (void)in_sizes; (void)n_in; (void)ws_size; (void)out_size;
}